// Round 7
// baseline (261.854 us; speedup 1.0000x reference)
//
#include <hip/hip_runtime.h>
#include <stdint.h>
#include <string.h>

#define NUM_NODES 17185
#define DD 6
#define FEATS (NUM_NODES * DD)   // 103110
#define BATCH 256
#define EPS 1e-5f

#define NT 128   // threads per block
#define NPB 256  // nodes per block (2 per thread)
#define BC 8     // batch rows per block
#define NCHUNK ((NUM_NODES + NPB - 1) / NPB)   // 68
#define TOTF ((size_t)BATCH * FEATS)

// ws: pm[NCHUNK*256] (row partials, chunk-major), pc[NCHUNK]. No atomics.

__device__ __forceinline__ void load16(float* dst, const float* src) {
    __builtin_memcpy(dst, src, 16);   // alignment-agnostic 16B load
}

__global__ __launch_bounds__(NT, 4) void main_kernel(
    const float* __restrict__ data, const float* __restrict__ wb, const float* __restrict__ bb,
    const float* __restrict__ gamma, const float* __restrict__ var, const float* __restrict__ fcw,
    const float* __restrict__ beta, const float* __restrict__ mean,
    float* __restrict__ pm, float* __restrict__ pc) {

    const int tid = threadIdx.x;
    const int bx = blockIdx.x;
    const int n0 = bx * NPB + 2 * tid;
    const int n1 = n0 + 1;
    const bool v0 = (n0 < NUM_NODES);
    const bool v1 = (n1 < NUM_NODES);

    float w[72], bias[12], aa[12];
    #pragma unroll
    for (int k = 0; k < 72; k++) w[k] = 0.f;
    #pragma unroll
    for (int k = 0; k < 12; k++) { bias[k] = 0.f; aa[k] = 0.f; }

    float cnode = 0.f;

    #pragma unroll
    for (int nn = 0; nn < 2; nn++) {
        const int n = n0 + nn;
        if (n < NUM_NODES) {
            const float4* wp = (const float4*)(wb + (size_t)n * 36);   // 144B stride, 16-aligned
            #pragma unroll
            for (int k = 0; k < 9; k++) {
                float4 v = wp[k];
                w[nn*36 + 4*k] = v.x; w[nn*36 + 4*k+1] = v.y;
                w[nn*36 + 4*k+2] = v.z; w[nn*36 + 4*k+3] = v.w;
            }
            const float2* bp = (const float2*)(bb + (size_t)n * 6);
            #pragma unroll
            for (int k = 0; k < 3; k++) { float2 v = bp[k]; bias[nn*6 + 2*k] = v.x; bias[nn*6 + 2*k+1] = v.y; }
            const int f0 = n * 6;
            const float2* gp = (const float2*)(gamma + f0);
            const float2* vp = (const float2*)(var + f0);
            const float2* fp = (const float2*)(fcw + f0);
            float fw[6];
            #pragma unroll
            for (int k = 0; k < 3; k++) {
                float2 g = gp[k], v = vp[k], f = fp[k];
                fw[2*k] = f.x; fw[2*k+1] = f.y;
                aa[nn*6 + 2*k]   = g.x * rsqrtf(v.x + EPS) * f.x;
                aa[nn*6 + 2*k+1] = g.y * rsqrtf(v.y + EPS) * f.y;
            }
            if (blockIdx.y == 0) {
                const float2* bep = (const float2*)(beta + f0);
                const float2* mp  = (const float2*)(mean + f0);
                #pragma unroll
                for (int k = 0; k < 3; k++) {
                    float2 be = bep[k], m = mp[k];
                    cnode += be.x * fw[2*k]   - m.x * aa[nn*6 + 2*k];
                    cnode += be.y * fw[2*k+1] - m.y * aa[nn*6 + 2*k+1];
                }
            }
        }
    }

    const int b0 = blockIdx.y * BC;
    float acc[BC];
    #pragma unroll
    for (int r = 0; r < BC; r++) acc[r] = 0.f;

    if (bx < NCHUNK - 1) {
        // Full chunk: all 256 nodes valid. 3 x 16B loads per row per thread.
        const float* base = data + (size_t)b0 * FEATS + (size_t)bx * (NPB * DD) + 12 * tid;
        #pragma unroll
        for (int r = 0; r < BC; r++) {
            const float* p = base + (size_t)r * FEATS;
            float x[12];
            load16(x,     p);
            load16(x + 4, p + 4);
            load16(x + 8, p + 8);
            #pragma unroll
            for (int nn = 0; nn < 2; nn++) {
                #pragma unroll
                for (int o = 0; o < 6; o++) {
                    float s = bias[nn*6 + o];
                    #pragma unroll
                    for (int i = 0; i < 6; i++)
                        s = fmaf(x[nn*6 + i], w[nn*36 + o*6 + i], s);
                    acc[r] = fmaf(fmaxf(s, 0.f), aa[nn*6 + o], acc[r]);
                }
            }
        }
    } else {
        // Last chunk: per-node guarded float2 loads.
        #pragma unroll
        for (int r = 0; r < BC; r++) {
            const int b = b0 + r;
            float x[12];
            #pragma unroll
            for (int k = 0; k < 12; k++) x[k] = 0.f;
            if (v0) {
                const float2* xp = (const float2*)(data + (size_t)b * FEATS + (size_t)n0 * 6);
                float2 u0 = xp[0], u1 = xp[1], u2 = xp[2];
                x[0] = u0.x; x[1] = u0.y; x[2] = u1.x; x[3] = u1.y; x[4] = u2.x; x[5] = u2.y;
            }
            if (v1) {
                const float2* xp = (const float2*)(data + (size_t)b * FEATS + (size_t)n1 * 6);
                float2 u0 = xp[0], u1 = xp[1], u2 = xp[2];
                x[6] = u0.x; x[7] = u0.y; x[8] = u1.x; x[9] = u1.y; x[10] = u2.x; x[11] = u2.y;
            }
            #pragma unroll
            for (int nn = 0; nn < 2; nn++) {
                #pragma unroll
                for (int o = 0; o < 6; o++) {
                    float s = bias[nn*6 + o];
                    #pragma unroll
                    for (int i = 0; i < 6; i++)
                        s = fmaf(x[nn*6 + i], w[nn*36 + o*6 + i], s);
                    acc[r] = fmaf(fmaxf(s, 0.f), aa[nn*6 + o], acc[r]);
                }
            }
        }
    }

    // Block reduction: 2 waves, BC independent shuffle chains.
    __shared__ float red[2][BC];
    #pragma unroll
    for (int r = 0; r < BC; r++) {
        float v = acc[r];
        #pragma unroll
        for (int off = 32; off; off >>= 1) v += __shfl_down(v, off);
        if ((tid & 63) == 0) red[tid >> 6][r] = v;
    }

    if (blockIdx.y == 0) {
        float v = cnode;
        #pragma unroll
        for (int off = 32; off; off >>= 1) v += __shfl_down(v, off);
        __shared__ float credd[2];
        if ((tid & 63) == 0) credd[tid >> 6] = v;
        __syncthreads();
        if (tid == 0) pc[bx] = credd[0] + credd[1];
    } else {
        __syncthreads();
    }

    if (tid < BC) {
        float s = red[0][tid] + red[1][tid];
        pm[bx * 256 + b0 + tid] = s;
    }
}

__global__ __launch_bounds__(256) void final_kernel(
    const float* __restrict__ pm, const float* __restrict__ pc,
    const float* __restrict__ fcb, const float* __restrict__ bnfg,
    const float* __restrict__ bnfb, const float* __restrict__ bnfm,
    const float* __restrict__ bnfv, float* __restrict__ out) {
    const int b = threadIdx.x;

    float c = (b < NCHUNK) ? pc[b] : 0.f;
    #pragma unroll
    for (int off = 32; off; off >>= 1) c += __shfl_down(c, off);
    __shared__ float red[4];
    if ((b & 63) == 0) red[b >> 6] = c;
    __syncthreads();
    const float c_sum = red[0] + red[1] + red[2] + red[3];

    float y = 0.f;
    #pragma unroll 8
    for (int ch = 0; ch < NCHUNK; ch++) y += pm[ch * 256 + b];   // coalesced

    y += c_sum + fcb[0];
    float sc = bnfg[0] * rsqrtf(bnfv[0] + EPS);
    float z = (y - bnfm[0]) * sc + bnfb[0];
    out[b] = 1.f / (1.f + expf(-z));
}

extern "C" void kernel_launch(void* const* d_in, const int* in_sizes, int n_in,
                              void* d_out, int out_size, void* d_ws, size_t ws_size,
                              hipStream_t stream) {
    const float* data  = (const float*)d_in[0];
    const float* wb    = (const float*)d_in[1];
    const float* bb    = (const float*)d_in[2];
    const float* gamma = (const float*)d_in[3];
    const float* beta  = (const float*)d_in[4];
    const float* mean  = (const float*)d_in[5];
    const float* var   = (const float*)d_in[6];
    const float* fcw   = (const float*)d_in[7];
    const float* fcb   = (const float*)d_in[8];
    const float* bnfg  = (const float*)d_in[9];
    const float* bnfb  = (const float*)d_in[10];
    const float* bnfm  = (const float*)d_in[11];
    const float* bnfv  = (const float*)d_in[12];

    float* pm = (float*)d_ws;                 // NCHUNK*256 floats
    float* pc = pm + NCHUNK * 256;            // NCHUNK floats

    dim3 grid(NCHUNK, BATCH / BC);            // (68, 32) = 2176 blocks x 2 waves
    main_kernel<<<grid, NT, 0, stream>>>(data, wb, bb, gamma, var, fcw, beta, mean, pm, pc);

    final_kernel<<<1, 256, 0, stream>>>(pm, pc, fcb, bnfg, bnfb, bnfm, bnfv, (float*)d_out);
}